// Round 8
// baseline (69.507 us; speedup 1.0000x reference)
//
#include <hip/hip_runtime.h>

typedef __bf16 bf16;
typedef __bf16 bf16x8 __attribute__((ext_vector_type(8)));
typedef __bf16 bf16x2 __attribute__((ext_vector_type(2)));
typedef float f32x16 __attribute__((ext_vector_type(16)));

#define BS 64
#define CI 64
#define LEN 4096
#define CO 128
#define KS 7
#define NK 4
#define HID 16
#define TEMP 30.0f

#define KTOT 448            // CI*KS
#define WROW 456            // padded wagg row (elems)
#define WBAT (CO * WROW)    // 58368 elems per batch
#define XROW 72             // padded x-tile row (i dim); 144B (16B-aligned rows)
#define XC 80               // staged window rows: [l0-8, l0+72)
#define LTILE 64
#define TPB 8               // L-tiles per block (512 l)

// ---------------- pool: mean over L ----------------
__global__ void pool_kernel(const float* __restrict__ x, float* __restrict__ pooled) {
    int bc = blockIdx.x;
    const float4* xp = (const float4*)(x + (size_t)bc * LEN);
    int t = threadIdx.x;
    float s = 0.f;
#pragma unroll
    for (int j = 0; j < 4; ++j) {
        float4 v = xp[t + 256 * j];
        s += (v.x + v.y) + (v.z + v.w);
    }
#pragma unroll
    for (int off = 32; off > 0; off >>= 1) s += __shfl_down(s, off, 64);
    __shared__ float red[4];
    if ((t & 63) == 0) red[t >> 6] = s;
    __syncthreads();
    if (t == 0) pooled[bc] = (red[0] + red[1] + red[2] + red[3]) * (1.0f / LEN);
}

// ---------------- aggw (+ attention recompute): 128 o x 2 b-halves ----------------
__global__ void aggw_kernel(const float* __restrict__ pooled,
                            const float* __restrict__ w1,
                            const float* __restrict__ w2,
                            const float* __restrict__ weight,
                            float* __restrict__ att_g,
                            bf16* __restrict__ wagg) {
    int o = blockIdx.x >> 1;
    int bh = blockIdx.x & 1;
    int t = threadIdx.x;
    __shared__ float p[32 * 64];              // 8 KB
    __shared__ float hsh[32 * 16];            // 2 KB
    __shared__ float att_s[32][4];
    __shared__ float lw[4 * KTOT];            // 7 KB   [bank][i*7+f]

    const float* wo = weight + (size_t)o * KTOT;
    for (int idx = t; idx < 4 * KTOT; idx += 256) {
        int bank = idx / KTOT;
        int r = idx - bank * KTOT;
        lw[idx] = wo[(size_t)bank * (CO * KTOT) + r];
    }
    for (int idx = t; idx < 32 * 64; idx += 256) p[idx] = pooled[bh * 2048 + idx];
    __syncthreads();

    {   // hidden: 32 b x 16 h, 2 per thread
        int bb = t >> 3, h2 = (t & 7) * 2;
#pragma unroll
        for (int u = 0; u < 2; ++u) {
            int hh = h2 + u;
            float s = 0.f;
            for (int i = 0; i < 64; ++i) s += p[bb * 64 + i] * w1[hh * 64 + i];
            hsh[bb * 16 + hh] = fmaxf(s, 0.f);
        }
    }
    __syncthreads();
    if (t < 32) {
        float lg[NK], m = -1e30f;
#pragma unroll
        for (int k = 0; k < NK; ++k) {
            float s = 0.f;
            for (int j = 0; j < HID; ++j) s += hsh[t * 16 + j] * w2[k * HID + j];
            lg[k] = s * (1.0f / TEMP);
            m = fmaxf(m, lg[k]);
        }
        float e[NK], tot = 0.f;
#pragma unroll
        for (int k = 0; k < NK; ++k) { e[k] = expf(lg[k] - m); tot += e[k]; }
        float inv = 1.0f / tot;
#pragma unroll
        for (int k = 0; k < NK; ++k) {
            att_s[t][k] = e[k] * inv;
            if (blockIdx.x < 2) att_g[(bh * 32 + t) * NK + k] = e[k] * inv;
        }
    }
    __syncthreads();

    if (t < 224) {                            // kout pair (2t, 2t+1), kout = f*64+i
        float w8[8];
#pragma unroll
        for (int j = 0; j < 2; ++j) {
            int kout = 2 * t + j;
            int i = kout & 63, f = kout >> 6;
#pragma unroll
            for (int bank = 0; bank < 4; ++bank)
                w8[j * 4 + bank] = lw[bank * KTOT + i * KS + f];
        }
        for (int bb = 0; bb < 32; ++bb) {
            int b = bh * 32 + bb;
            float a0 = att_s[bb][0], a1 = att_s[bb][1];
            float a2 = att_s[bb][2], a3 = att_s[bb][3];
            float v0 = a0 * w8[0] + a1 * w8[1] + a2 * w8[2] + a3 * w8[3];
            float v1 = a0 * w8[4] + a1 * w8[5] + a2 * w8[6] + a3 * w8[7];
            bf16x2 pk; pk[0] = (bf16)v0; pk[1] = (bf16)v1;
            *(bf16x2*)(wagg + (size_t)b * WBAT + o * WROW + 2 * t) = pk;
        }
    }
}

// ---------------- conv: implicit GEMM, 32x32x16 MFMA, 128o x 64l tiles ----------------
struct XStage { float4 m[5]; };

__global__ __launch_bounds__(256, 2) void conv_kernel(
    const float* __restrict__ x,
    const bf16* __restrict__ wagg,
    const float* __restrict__ att_g,
    const float* __restrict__ bias,
    float* __restrict__ out) {
    __shared__ __align__(16) bf16 lds_x[2][XC * XROW];   // 2 x 11520 B
    __shared__ float aggb_l[CO];

    int nwg = gridDim.x;                               // 512 (mult of 8)
    int bid = blockIdx.x;
    int logical = (bid & 7) * (nwg >> 3) + (bid >> 3); // XCD-chunked swizzle (T1)
    int b = logical >> 3;
    int lsp = logical & 7;

    int t = threadIdx.x;
    int lane = t & 63, wid = t >> 6;                   // wave: o = wid*32 .. +31
    int l31 = lane & 31, hi = lane >> 5;

    // aggregated bias for all 128 o into LDS
    if (t < CO) {
        float a0 = att_g[b * NK + 0], a1 = att_g[b * NK + 1];
        float a2 = att_g[b * NK + 2], a3 = att_g[b * NK + 3];
        aggb_l[t] = a0 * bias[0 * CO + t] + a1 * bias[1 * CO + t] +
                    a2 * bias[2 * CO + t] + a3 * bias[3 * CO + t];
    }

    // ---- A-fragments (W) into registers: 28 x bf16x8 = 112 VGPR ----
    // 32x32x16 A layout: m = lane&31, k = kk*16 + (lane>>5)*8 + j
    const bf16* wgb = wagg + (size_t)b * WBAT
                    + (size_t)(wid * 32 + l31) * WROW + hi * 8;
    bf16x8 av[28];
#pragma unroll
    for (int kk = 0; kk < 28; ++kk)
        av[kk] = *(const bf16x8*)(wgb + kk * 16);

    int l0base = lsp * (LTILE * TPB);
    int si = t >> 2, sf = t & 3;                       // thread stages cols [20sf,20sf+20) of row si
    const float* xb = x + (size_t)b * CI * LEN;

    auto load_x = [&](int l0, XStage& s, bool guard) {
        int g0 = l0 - 8;
        if (!guard) {
#pragma unroll
            for (int m = 0; m < 5; ++m)
                s.m[m] = *(const float4*)(xb + (size_t)si * LEN + g0 + 20 * sf + 4 * m);
        } else {
#pragma unroll
            for (int m = 0; m < 5; ++m) {
                int cb = g0 + 20 * sf + 4 * m;
#pragma unroll
                for (int e = 0; e < 4; ++e) {
                    int c = cb + e;
                    (&s.m[m].x)[e] = (c >= 0 && c < LEN) ? xb[(size_t)si * LEN + c] : 0.f;
                }
            }
        }
    };
    auto write_x = [&](int buf, const XStage& s) {
        bf16* lb = lds_x[buf];
#pragma unroll
        for (int m = 0; m < 5; ++m)
#pragma unroll
            for (int e = 0; e < 4; ++e) {
                int c = 20 * sf + 4 * m + e;
                lb[c * XROW + si] = (bf16)((&s.m[m].x)[e]);
            }
    };

    XStage s0;
    load_x(l0base, s0, lsp == 0);
    write_x(0, s0);
    __syncthreads();

    // per-thread bias for its 16 output rows (row = (reg&3)+8*(reg>>2)+4*hi)
    float bias_r[16];
#pragma unroll
    for (int reg = 0; reg < 16; ++reg)
        bias_r[reg] = aggb_l[wid * 32 + (reg & 3) + 8 * (reg >> 2) + 4 * hi];

    size_t orow0 = ((size_t)(b * CO + wid * 32)) * LEN;

    for (int tl = 0; tl < TPB; ++tl) {
        int l0 = l0base + tl * LTILE;
        XStage sn;
        if (tl + 1 < TPB)
            load_x(l0 + LTILE, sn, (lsp == 7) && (tl + 1 == TPB - 1));   // T14 early issue

        f32x16 acc0 = {}, acc1 = {};
        const bf16* lb = lds_x[tl & 1];
        // bv row = nf*32 + l31 + 5 + f, col = (kk&3)*16 + hi*8 ; f = kk>>2
        const bf16* bp = lb + (size_t)(l31 + 5) * XROW + hi * 8;

#pragma unroll
        for (int kk = 0; kk < 28; ++kk) {
            int boff = (kk >> 2) * XROW + (kk & 3) * 16;
            bf16x8 bv0 = *(const bf16x8*)(bp + boff);
            bf16x8 bv1 = *(const bf16x8*)(bp + 32 * XROW + boff);
            acc0 = __builtin_amdgcn_mfma_f32_32x32x16_bf16(av[kk], bv0, acc0, 0, 0, 0);
            acc1 = __builtin_amdgcn_mfma_f32_32x32x16_bf16(av[kk], bv1, acc1, 0, 0, 0);
        }

        // ---- store: per reg, 2 rows x 128B contiguous ----
#pragma unroll
        for (int reg = 0; reg < 16; ++reg) {
            int row = (reg & 3) + 8 * (reg >> 2) + 4 * hi;
            size_t rbase = orow0 + (size_t)row * LEN + l0 + l31;
            out[rbase] = acc0[reg] + bias_r[reg];
            out[rbase + 32] = acc1[reg] + bias_r[reg];
        }

        if (tl + 1 < TPB) {
            write_x((tl + 1) & 1, sn);   // other buffer; prior reads done pre-barrier
            __syncthreads();
        }
    }
}

extern "C" void kernel_launch(void* const* d_in, const int* in_sizes, int n_in,
                              void* d_out, int out_size, void* d_ws, size_t ws_size,
                              hipStream_t stream) {
    const float* x  = (const float*)d_in[0];
    const float* w1 = (const float*)d_in[1];
    const float* w2 = (const float*)d_in[2];
    const float* wt = (const float*)d_in[3];
    const float* bs = (const float*)d_in[4];
    float* out = (float*)d_out;

    bf16* wagg = (bf16*)d_ws;                              // 7,471,104 B
    float* pooled = (float*)((char*)d_ws + (size_t)BS * WBAT * 2);
    float* att_g  = pooled + BS * CI;

    pool_kernel<<<BS * CI, 256, 0, stream>>>(x, pooled);
    aggw_kernel<<<CO * 2, 256, 0, stream>>>(pooled, w1, w2, wt, att_g, wagg);
    conv_kernel<<<BS * 8, 256, 0, stream>>>(x, wagg, att_g, bs, out);
}

// Round 9
// 66.591 us; speedup vs baseline: 1.0438x; 1.0438x over previous
//
#include <hip/hip_runtime.h>

typedef __bf16 bf16;
typedef __bf16 bf16x8 __attribute__((ext_vector_type(8)));
typedef __bf16 bf16x2 __attribute__((ext_vector_type(2)));
typedef float f32x4 __attribute__((ext_vector_type(4)));

#define BS 64
#define CI 64
#define LEN 4096
#define CO 128
#define KS 7
#define NK 4
#define HID 16
#define TEMP 30.0f

#define KTOT 448            // CI*KS
#define WROW 456            // padded wagg row (elems)
#define WBAT (CO * WROW)    // 58368 elems per batch
#define XROW 72             // padded x-tile row (i dim); 144B
#define XC 134              // l-window 128 + 6 halo
#define LTILE 128
#define TPB 8               // L-tiles per block (1024 l)

// ---------------- pool: mean over L ----------------
__global__ void pool_kernel(const float* __restrict__ x, float* __restrict__ pooled) {
    int bc = blockIdx.x;
    const float4* xp = (const float4*)(x + (size_t)bc * LEN);
    int t = threadIdx.x;
    float s = 0.f;
#pragma unroll
    for (int j = 0; j < 4; ++j) {
        float4 v = xp[t + 256 * j];
        s += (v.x + v.y) + (v.z + v.w);
    }
#pragma unroll
    for (int off = 32; off > 0; off >>= 1) s += __shfl_down(s, off, 64);
    __shared__ float red[4];
    if ((t & 63) == 0) red[t >> 6] = s;
    __syncthreads();
    if (t == 0) pooled[bc] = (red[0] + red[1] + red[2] + red[3]) * (1.0f / LEN);
}

// ---------------- aggw (+ attention recompute): 128 o x 2 b-halves ----------------
__global__ void aggw_kernel(const float* __restrict__ pooled,
                            const float* __restrict__ w1,
                            const float* __restrict__ w2,
                            const float* __restrict__ weight,
                            float* __restrict__ att_g,
                            bf16* __restrict__ wagg) {
    int o = blockIdx.x >> 1;
    int bh = blockIdx.x & 1;
    int t = threadIdx.x;
    __shared__ float p[32 * 64];              // 8 KB
    __shared__ float hsh[32 * 16];            // 2 KB
    __shared__ float att_s[32][4];
    __shared__ float lw[4 * KTOT];            // 7 KB   [bank][i*7+f]

    const float* wo = weight + (size_t)o * KTOT;
    for (int idx = t; idx < 4 * KTOT; idx += 256) {
        int bank = idx / KTOT;
        int r = idx - bank * KTOT;
        lw[idx] = wo[(size_t)bank * (CO * KTOT) + r];
    }
    for (int idx = t; idx < 32 * 64; idx += 256) p[idx] = pooled[bh * 2048 + idx];
    __syncthreads();

    {   // hidden: 32 b x 16 h, 2 per thread
        int bb = t >> 3, h2 = (t & 7) * 2;
#pragma unroll
        for (int u = 0; u < 2; ++u) {
            int hh = h2 + u;
            float s = 0.f;
            for (int i = 0; i < 64; ++i) s += p[bb * 64 + i] * w1[hh * 64 + i];
            hsh[bb * 16 + hh] = fmaxf(s, 0.f);
        }
    }
    __syncthreads();
    if (t < 32) {
        float lg[NK], m = -1e30f;
#pragma unroll
        for (int k = 0; k < NK; ++k) {
            float s = 0.f;
            for (int j = 0; j < HID; ++j) s += hsh[t * 16 + j] * w2[k * HID + j];
            lg[k] = s * (1.0f / TEMP);
            m = fmaxf(m, lg[k]);
        }
        float e[NK], tot = 0.f;
#pragma unroll
        for (int k = 0; k < NK; ++k) { e[k] = expf(lg[k] - m); tot += e[k]; }
        float inv = 1.0f / tot;
#pragma unroll
        for (int k = 0; k < NK; ++k) {
            att_s[t][k] = e[k] * inv;
            if (blockIdx.x < 2) att_g[(bh * 32 + t) * NK + k] = e[k] * inv;
        }
    }
    __syncthreads();

    if (t < 224) {                            // kout pair (2t, 2t+1), kout = f*64+i
        float w8[8];
#pragma unroll
        for (int j = 0; j < 2; ++j) {
            int kout = 2 * t + j;
            int i = kout & 63, f = kout >> 6;
#pragma unroll
            for (int bank = 0; bank < 4; ++bank)
                w8[j * 4 + bank] = lw[bank * KTOT + i * KS + f];
        }
        for (int bb = 0; bb < 32; ++bb) {
            int b = bh * 32 + bb;
            float a0 = att_s[bb][0], a1 = att_s[bb][1];
            float a2 = att_s[bb][2], a3 = att_s[bb][3];
            float v0 = a0 * w8[0] + a1 * w8[1] + a2 * w8[2] + a3 * w8[3];
            float v1 = a0 * w8[4] + a1 * w8[5] + a2 * w8[6] + a3 * w8[7];
            bf16x2 pk; pk[0] = (bf16)v0; pk[1] = (bf16)v1;
            *(bf16x2*)(wagg + (size_t)b * WBAT + o * WROW + 2 * t) = pk;
        }
    }
}

// ---------------- conv: implicit GEMM, W in regs, stores after barrier ----------------
struct XStage { float4 m[8]; float e1, e2; };

__global__ __launch_bounds__(256, 2) void conv_kernel(
    const float* __restrict__ x,
    const bf16* __restrict__ wagg,
    const float* __restrict__ att_g,
    const float* __restrict__ bias,
    float* __restrict__ out) {
    __shared__ __align__(16) bf16 lds_x[2][XC * XROW];   // 2 x 19296 B
    __shared__ float aggb_l[CO];

    int nwg = gridDim.x;                               // 512 (mult of 8)
    int bid = blockIdx.x;
    int logical = (bid & 7) * (nwg >> 3) + (bid >> 3); // XCD-chunked swizzle (T1)
    int b = logical >> 3;
    int rem = logical & 7;
    int oh = rem >> 2, lsp = rem & 3;

    int t = threadIdx.x;
    int lane = t & 63, wid = t >> 6;
    int ln = lane & 15, g = lane >> 4;
    int wm = wid >> 1, wn = wid & 1;                   // wave tile: 32 o x 64 l

    // aggregated bias for all 128 o into LDS
    if (t < CO) {
        float a0 = att_g[b * NK + 0], a1 = att_g[b * NK + 1];
        float a2 = att_g[b * NK + 2], a3 = att_g[b * NK + 3];
        aggb_l[t] = a0 * bias[0 * CO + t] + a1 * bias[1 * CO + t] +
                    a2 * bias[2 * CO + t] + a3 * bias[3 * CO + t];
    }

    // ---- A-fragments (W) into registers, once per 1024 l ----
    const bf16* wgb = wagg + (size_t)b * WBAT
                    + (size_t)(oh * 64 + wm * 32 + ln) * WROW + g * 8;
    bf16x8 av[2][14];
#pragma unroll
    for (int mf = 0; mf < 2; ++mf)
#pragma unroll
        for (int kk = 0; kk < 14; ++kk)
            av[mf][kk] = *(const bf16x8*)(wgb + mf * 16 * WROW + kk * 32);

    int l0base = lsp * (LTILE * TPB);
    int si = t >> 2, sf = t & 3;
    const float* xb = x + (size_t)b * CI * LEN;

    auto load_x = [&](int l0, XStage& s) {
#pragma unroll
        for (int j = 0; j < 8; ++j) {
            int c4 = sf + 4 * j;
            s.m[j] = *(const float4*)(xb + (size_t)si * LEN + l0 + 4 * c4);
        }
        int i1 = t / 6, s1 = t - i1 * 6;
        int c1 = (s1 < 3) ? s1 : (128 + s1);
        int gl1 = l0 - 3 + c1;
        s.e1 = (gl1 >= 0 && gl1 < LEN) ? xb[(size_t)i1 * LEN + gl1] : 0.f;
        s.e2 = 0.f;
        if (t < 128) {
            int e2 = 256 + t, i2 = e2 / 6, s2 = e2 - i2 * 6;
            int c2 = (s2 < 3) ? s2 : (128 + s2);
            int gl2 = l0 - 3 + c2;
            s.e2 = (gl2 >= 0 && gl2 < LEN) ? xb[(size_t)i2 * LEN + gl2] : 0.f;
        }
    };
    auto write_x = [&](int buf, const XStage& s) {
        bf16* lb = lds_x[buf];
#pragma unroll
        for (int j = 0; j < 8; ++j) {
            int c4 = sf + 4 * j;
#pragma unroll
            for (int dl = 0; dl < 4; ++dl) {
                float v = (&s.m[j].x)[dl];
                lb[(4 * c4 + 3 + dl) * XROW + si] = (bf16)v;
            }
        }
        int i1 = t / 6, s1 = t - i1 * 6;
        int c1 = (s1 < 3) ? s1 : (128 + s1);
        lb[c1 * XROW + i1] = (bf16)s.e1;
        if (t < 128) {
            int e2 = 256 + t, i2 = e2 / 6, s2 = e2 - i2 * 6;
            int c2 = (s2 < 3) ? s2 : (128 + s2);
            lb[c2 * XROW + i2] = (bf16)s.e2;
        }
    };

    XStage s0;
    load_x(l0base, s0);
    write_x(0, s0);
    __syncthreads();

    // bias + output row offsets: o = oh*64 + wm*32 + mf*16 + g*4 + r
    float bias_r[2][4];
    int orow_off[2][4];
#pragma unroll
    for (int mf = 0; mf < 2; ++mf)
#pragma unroll
        for (int r = 0; r < 4; ++r) {
            int o = oh * 64 + wm * 32 + mf * 16 + g * 4 + r;
            bias_r[mf][r] = aggb_l[o];
            orow_off[mf][r] = (b * CO + o) * LEN;
        }

    for (int tl = 0; tl < TPB; ++tl) {
        int l0 = l0base + tl * LTILE;
        XStage sn;
        if (tl + 1 < TPB) load_x(l0 + LTILE, sn);   // issue early (T14)

        f32x4 acc[2][4];
#pragma unroll
        for (int mf = 0; mf < 2; ++mf)
#pragma unroll
            for (int nf = 0; nf < 4; ++nf)
                acc[mf][nf] = (f32x4){0.f, 0.f, 0.f, 0.f};

        const bf16* bp = lds_x[tl & 1] + (wn * 64 + ln) * XROW + g * 8;

#pragma unroll
        for (int kk = 0; kk < 14; ++kk) {
            int boff = (kk >> 1) * XROW + (kk & 1) * 32;   // f-shift rows, i-half cols
            bf16x8 bv[4];
#pragma unroll
            for (int nf = 0; nf < 4; ++nf)
                bv[nf] = *(const bf16x8*)(bp + nf * 16 * XROW + boff);
#pragma unroll
            for (int mf = 0; mf < 2; ++mf)
#pragma unroll
                for (int nf = 0; nf < 4; ++nf)
                    acc[mf][nf] = __builtin_amdgcn_mfma_f32_16x16x32_bf16(
                        av[mf][kk], bv[nf], acc[mf][nf], 0, 0, 0);
        }

        // stage next tile into the OTHER buffer, then barrier, THEN store:
        // the pre-barrier vmcnt drain no longer waits on our output stores,
        // and stores of tile tl overlap the K-loop of tile tl+1.
        if (tl + 1 < TPB) {
            write_x((tl + 1) & 1, sn);
            __syncthreads();
        }

#pragma unroll
        for (int mf = 0; mf < 2; ++mf)
#pragma unroll
            for (int nf = 0; nf < 4; ++nf) {
                int l = l0 + wn * 64 + nf * 16 + ln;
#pragma unroll
                for (int r = 0; r < 4; ++r)
                    out[(size_t)orow_off[mf][r] + l] = acc[mf][nf][r] + bias_r[mf][r];
            }
    }
}

extern "C" void kernel_launch(void* const* d_in, const int* in_sizes, int n_in,
                              void* d_out, int out_size, void* d_ws, size_t ws_size,
                              hipStream_t stream) {
    const float* x  = (const float*)d_in[0];
    const float* w1 = (const float*)d_in[1];
    const float* w2 = (const float*)d_in[2];
    const float* wt = (const float*)d_in[3];
    const float* bs = (const float*)d_in[4];
    float* out = (float*)d_out;

    bf16* wagg = (bf16*)d_ws;                              // 7,471,104 B
    float* pooled = (float*)((char*)d_ws + (size_t)BS * WBAT * 2);
    float* att_g  = pooled + BS * CI;

    pool_kernel<<<BS * CI, 256, 0, stream>>>(x, pooled);
    aggw_kernel<<<CO * 2, 256, 0, stream>>>(pooled, w1, w2, wt, att_g, wagg);
    conv_kernel<<<BS * 8, 256, 0, stream>>>(x, wagg, att_g, bs, out);
}

// Round 10
// 66.060 us; speedup vs baseline: 1.0522x; 1.0080x over previous
//
#include <hip/hip_runtime.h>

typedef __bf16 bf16;
typedef __bf16 bf16x8 __attribute__((ext_vector_type(8)));
typedef __bf16 bf16x2 __attribute__((ext_vector_type(2)));
typedef float f32x4 __attribute__((ext_vector_type(4)));

#define BS 64
#define CI 64
#define LEN 4096
#define CO 128
#define KS 7
#define NK 4
#define HID 16
#define TEMP 30.0f

#define KTOT 448            // CI*KS
#define WROW 456            // padded wagg row (elems)
#define WBAT (CO * WROW)    // 58368 elems per batch
#define LTILE 128
#define TPB 8               // L-tiles per conv block (1024 l)
#define XB_ROWS 4112        // 8 guard + 4096 + 8 guard
#define XB_ELE (XB_ROWS * 64)

// direct global->LDS DMA, 16B per lane (CK-style addrspace casts)
__device__ __forceinline__ void gl_lds16(const void* g, void* l) {
    auto gp = reinterpret_cast<const __attribute__((address_space(1))) unsigned int*>(
        reinterpret_cast<unsigned long long>(g));
    auto lp = reinterpret_cast<__attribute__((address_space(3))) unsigned int*>(
        reinterpret_cast<unsigned long long>(l));
    __builtin_amdgcn_global_load_lds(gp, lp, 16, 0, 0);
}

// ---------------- transpose + pool partials ----------------
// xbf[b][gl][i]: gl = l + 8, 64 bf16 per row (128 B), chunk c at byte 16*(c^(gl&7)).
// part[b][lt][i] = sum over this block's 512 l.
__global__ __launch_bounds__(256) void trans_kernel(const float* __restrict__ x,
                                                    bf16* __restrict__ xbf,
                                                    float* __restrict__ part) {
    int bid = blockIdx.x;
    int b = bid >> 3, lt = bid & 7;
    int t = threadIdx.x;
    int si = t >> 2, sf = t & 3;
    __shared__ __align__(16) bf16 lds_t[128 * 72];
    __shared__ float lds_red[64 * 4];

    const float* xb = x + (size_t)b * CI * LEN;
    bf16* xo = xbf + (size_t)b * XB_ELE;
    float psum = 0.f;

    for (int st = 0; st < 4; ++st) {
        int ls = lt * 512 + st * 128;
        float4 v[8];
#pragma unroll
        for (int j = 0; j < 8; ++j)
            v[j] = *(const float4*)(xb + (size_t)si * LEN + ls + 4 * (sf + 4 * j));
#pragma unroll
        for (int j = 0; j < 8; ++j) {
            psum += (v[j].x + v[j].y) + (v[j].z + v[j].w);
#pragma unroll
            for (int e = 0; e < 4; ++e)
                lds_t[(4 * (sf + 4 * j) + e) * 72 + si] = (bf16)((&v[j].x)[e]);
        }
        __syncthreads();
        int row = t >> 4, l16 = t & 15;
#pragma unroll
        for (int pass = 0; pass < 8; ++pass) {
            int r = pass * 16 + row;
            int gl = ls + r + 8;
            uint2 d = *(const uint2*)(lds_t + r * 72 + l16 * 4);
            int c = l16 >> 1;
            int sw = c ^ (gl & 7);
            *(uint2*)((char*)xo + (size_t)gl * 128 + sw * 16 + (l16 & 1) * 8) = d;
        }
        __syncthreads();
    }

    lds_red[si * 4 + sf] = psum;
    __syncthreads();
    if (t < 64)
        part[((size_t)b * 8 + lt) * 64 + t] =
            lds_red[t * 4] + lds_red[t * 4 + 1] + lds_red[t * 4 + 2] + lds_red[t * 4 + 3];

    // zero guard rows (plain zeros; swizzle of zeros is zeros)
    if (lt == 0 && t < 128) *(uint2*)((char*)xo + t * 8) = make_uint2(0u, 0u);
    if (lt == 7 && t < 128) *(uint2*)((char*)xo + (size_t)4104 * 128 + t * 8) = make_uint2(0u, 0u);
}

// ---------------- aggw (+ attention recompute from partials) ----------------
__global__ void aggw_kernel(const float* __restrict__ part,
                            const float* __restrict__ w1,
                            const float* __restrict__ w2,
                            const float* __restrict__ weight,
                            float* __restrict__ att_g,
                            bf16* __restrict__ wagg) {
    int o = blockIdx.x >> 1;
    int bh = blockIdx.x & 1;
    int t = threadIdx.x;
    __shared__ float p[32 * 64];
    __shared__ float hsh[32 * 16];
    __shared__ float att_s[32][4];
    __shared__ float lw[4 * KTOT];

    const float* wo = weight + (size_t)o * KTOT;
    for (int idx = t; idx < 4 * KTOT; idx += 256) {
        int bank = idx / KTOT;
        int r = idx - bank * KTOT;
        lw[idx] = wo[(size_t)bank * (CO * KTOT) + r];
    }
    for (int idx = t; idx < 32 * 64; idx += 256) {
        int bb = idx >> 6, i = idx & 63;
        const float* pp = part + ((size_t)(bh * 32 + bb) * 8) * 64 + i;
        float s = 0.f;
#pragma unroll
        for (int j = 0; j < 8; ++j) s += pp[j * 64];
        p[idx] = s * (1.0f / LEN);
    }
    __syncthreads();

    {   // hidden: 32 b x 16 h, 2 per thread
        int bb = t >> 3, h2 = (t & 7) * 2;
#pragma unroll
        for (int u = 0; u < 2; ++u) {
            int hh = h2 + u;
            float s = 0.f;
            for (int i = 0; i < 64; ++i) s += p[bb * 64 + i] * w1[hh * 64 + i];
            hsh[bb * 16 + hh] = fmaxf(s, 0.f);
        }
    }
    __syncthreads();
    if (t < 32) {
        float lg[NK], m = -1e30f;
#pragma unroll
        for (int k = 0; k < NK; ++k) {
            float s = 0.f;
            for (int j = 0; j < HID; ++j) s += hsh[t * 16 + j] * w2[k * HID + j];
            lg[k] = s * (1.0f / TEMP);
            m = fmaxf(m, lg[k]);
        }
        float e[NK], tot = 0.f;
#pragma unroll
        for (int k = 0; k < NK; ++k) { e[k] = expf(lg[k] - m); tot += e[k]; }
        float inv = 1.0f / tot;
#pragma unroll
        for (int k = 0; k < NK; ++k) {
            att_s[t][k] = e[k] * inv;
            if (blockIdx.x < 2) att_g[(bh * 32 + t) * NK + k] = e[k] * inv;
        }
    }
    __syncthreads();

    if (t < 224) {                            // kout pair (2t, 2t+1), kout = f*64+i
        float w8[8];
#pragma unroll
        for (int j = 0; j < 2; ++j) {
            int kout = 2 * t + j;
            int i = kout & 63, f = kout >> 6;
#pragma unroll
            for (int bank = 0; bank < 4; ++bank)
                w8[j * 4 + bank] = lw[bank * KTOT + i * KS + f];
        }
        for (int bb = 0; bb < 32; ++bb) {
            int b = bh * 32 + bb;
            float a0 = att_s[bb][0], a1 = att_s[bb][1];
            float a2 = att_s[bb][2], a3 = att_s[bb][3];
            float v0 = a0 * w8[0] + a1 * w8[1] + a2 * w8[2] + a3 * w8[3];
            float v1 = a0 * w8[4] + a1 * w8[5] + a2 * w8[6] + a3 * w8[7];
            bf16x2 pk; pk[0] = (bf16)v0; pk[1] = (bf16)v1;
            *(bf16x2*)(wagg + (size_t)b * WBAT + o * WROW + 2 * t) = pk;
        }
    }
}

// ---------------- conv: implicit GEMM, DMA-staged swizzled x, W in regs ----------------
__global__ __launch_bounds__(256, 2) void conv_kernel(
    const bf16* __restrict__ xbf,
    const bf16* __restrict__ wagg,
    const float* __restrict__ att_g,
    const float* __restrict__ bias,
    float* __restrict__ out) {
    __shared__ __align__(1024) bf16 lds_x[2][144 * 64];   // 2 x 18432 B
    __shared__ float aggb_l[CO];

    int nwg = gridDim.x;                               // 512 (mult of 8)
    int bid = blockIdx.x;
    int logical = (bid & 7) * (nwg >> 3) + (bid >> 3); // XCD-chunked swizzle (T1)
    int b = logical >> 3;
    int rem = logical & 7;
    int oh = rem >> 2, lsp = rem & 3;

    int t = threadIdx.x;
    int lane = t & 63, wid = t >> 6;
    int ln = lane & 15, g = lane >> 4;
    int wm = wid >> 1, wn = wid & 1;                   // wave tile: 32 o x 64 l

    if (t < CO) {
        float a0 = att_g[b * NK + 0], a1 = att_g[b * NK + 1];
        float a2 = att_g[b * NK + 2], a3 = att_g[b * NK + 3];
        aggb_l[t] = a0 * bias[0 * CO + t] + a1 * bias[1 * CO + t] +
                    a2 * bias[2 * CO + t] + a3 * bias[3 * CO + t];
    }

    // A-fragments (W) into registers, once per 1024 l
    const bf16* wgb = wagg + (size_t)b * WBAT
                    + (size_t)(oh * 64 + wm * 32 + ln) * WROW + g * 8;
    bf16x8 av[2][14];
#pragma unroll
    for (int mf = 0; mf < 2; ++mf)
#pragma unroll
        for (int kk = 0; kk < 14; ++kk)
            av[mf][kk] = *(const bf16x8*)(wgb + mf * 16 * WROW + kk * 32);

    int l0base = lsp * (LTILE * TPB);
    const bf16* xb = xbf + (size_t)b * XB_ELE;

    auto stage = [&](int buf, int l0) {
        // stage physical rows gl = l0 .. l0+143 (l = l0-8 .. l0+135), contiguous 18432 B
        const char* src = (const char*)xb + (size_t)l0 * 128 + lane * 16;
        char* dst = (char*)lds_x[buf];
        for (int c = wid; c < 18; c += 4)
            gl_lds16(src + c * 1024, dst + c * 1024);
    };

    stage(0, l0base);
    __syncthreads();   // compiler drains vmcnt before barrier -> staging complete

    // bias + output row offsets: o = oh*64 + wm*32 + mf*16 + g*4 + r
    float bias_r[2][4];
    int orow_off[2][4];
#pragma unroll
    for (int mf = 0; mf < 2; ++mf)
#pragma unroll
        for (int r = 0; r < 4; ++r) {
            int o = oh * 64 + wm * 32 + mf * 16 + g * 4 + r;
            bias_r[mf][r] = aggb_l[o];
            orow_off[mf][r] = (b * CO + o) * LEN;
        }

    int prow = wn * 64 + ln + 5;    // LDS row for nf=0, f=0

    for (int tl = 0; tl < TPB; ++tl) {
        int l0 = l0base + tl * LTILE;
        if (tl + 1 < TPB) stage((tl + 1) & 1, l0 + LTILE);   // DMA into other buffer

        f32x4 acc[2][4];
#pragma unroll
        for (int mf = 0; mf < 2; ++mf)
#pragma unroll
            for (int nf = 0; nf < 4; ++nf)
                acc[mf][nf] = (f32x4){0.f, 0.f, 0.f, 0.f};

        const char* lb = (const char*)lds_x[tl & 1];

#pragma unroll
        for (int kk = 0; kk < 14; ++kk) {
            int f = kk >> 1;
            int key = (prow + f) & 7;                 // = row&7 for all nf (nf*16 = 0 mod 8)
            int swz = (((kk & 1) * 4 + g) ^ key) * 16; // swizzled 16B chunk within row
            bf16x8 bv[4];
#pragma unroll
            for (int nf = 0; nf < 4; ++nf)
                bv[nf] = *(const bf16x8*)(lb + (prow + nf * 16 + f) * 128 + swz);
#pragma unroll
            for (int mf = 0; mf < 2; ++mf)
#pragma unroll
                for (int nf = 0; nf < 4; ++nf)
                    acc[mf][nf] = __builtin_amdgcn_mfma_f32_16x16x32_bf16(
                        av[mf][kk], bv[nf], acc[mf][nf], 0, 0, 0);
        }

        if (tl + 1 < TPB) __syncthreads();   // drains staging DMA; stores overlap next K-loop

#pragma unroll
        for (int mf = 0; mf < 2; ++mf)
#pragma unroll
            for (int nf = 0; nf < 4; ++nf) {
                int l = l0 + wn * 64 + nf * 16 + ln;
#pragma unroll
                for (int r = 0; r < 4; ++r)
                    out[(size_t)orow_off[mf][r] + l] = acc[mf][nf][r] + bias_r[mf][r];
            }
    }
}

extern "C" void kernel_launch(void* const* d_in, const int* in_sizes, int n_in,
                              void* d_out, int out_size, void* d_ws, size_t ws_size,
                              hipStream_t stream) {
    const float* x  = (const float*)d_in[0];
    const float* w1 = (const float*)d_in[1];
    const float* w2 = (const float*)d_in[2];
    const float* wt = (const float*)d_in[3];
    const float* bs = (const float*)d_in[4];
    float* out = (float*)d_out;

    bf16* xbf    = (bf16*)d_ws;                                        // 33,685,504 B
    bf16* wagg   = (bf16*)((char*)d_ws + (size_t)BS * XB_ELE * 2);     // 7,471,104 B
    float* part  = (float*)((char*)wagg + (size_t)BS * WBAT * 2);      // 131,072 B
    float* att_g = part + BS * 8 * 64;                                 // 1,024 B

    trans_kernel<<<BS * 8, 256, 0, stream>>>(x, xbf, part);
    aggw_kernel<<<CO * 2, 256, 0, stream>>>(part, w1, w2, wt, att_g, wagg);
    conv_kernel<<<BS * 8, 256, 0, stream>>>(xbf, wagg, att_g, bs, out);
}